// Round 13
// baseline (1226.802 us; speedup 1.0000x reference)
//
#include <hip/hip_runtime.h>
#include <hip/hip_bf16.h>
#include <stdint.h>

typedef __attribute__((ext_vector_type(8))) short short8;
typedef __attribute__((ext_vector_type(4))) float f32x4;

#define N_DRUG 708
#define N_TGT  1512
#define N_NODES 7823
#define N_D_T  2220          // 708+1512
#define KPAD   8192          // 128 * 64
#define MROWP  7936          // 62 * 128 (adjb row pad)
#define NTOT   2002688       // 7823*256
#define NSPLIT 4
#define PLANE  61199329LL    // 7823*7823
#define ADJSTR ((long long)MROWP*KPAD)     // adjb batch stride (elems)
#define BTSTR  ((long long)256*KPAD)       // xw1T/hw2T batch stride
#define PSTR   ((long long)NSPLIT*NTOT)    // parts batch stride

__device__ __forceinline__ unsigned short f2bf(float f) {
  union { float f; unsigned int i; } v; v.f = f;
  unsigned int r = v.i + 0x7FFF + ((v.i >> 16) & 1);
  return (unsigned short)(r >> 16);
}

__device__ __forceinline__ int4 pack8(const float v[8]) {
  union { int4 i4; unsigned short u[8]; } r;
  #pragma unroll
  for (int j = 0; j < 8; j++) r.u[j] = f2bf(v[j]);
  return r.i4;
}

// ---------------------------------------------------------------- cast kernels

__global__ __launch_bounds__(256) void cast_wc(
    const float* __restrict__ w0, const float* __restrict__ wr0,
    const float* __restrict__ w1, const float* __restrict__ wr1,
    const float* __restrict__ w2, const float* __restrict__ wr2,
    unsigned short* __restrict__ Wc)
{
  long long i4 = ((long long)blockIdx.x*256 + threadIdx.x)*4;
  int g  = (int)(i4 >> 20);
  int rr = (int)((i4 >> 10) & 1023);
  int c  = (int)(i4 & 1023);
  const float* src = (g==0) ? (rr<512?w0:wr0) : (g==1) ? (rr<512?w1:wr1) : (rr<512?w2:wr2);
  float4 f = *(const float4*)(src + (long long)(rr & 511)*1024 + c);
  ushort4 v; v.x=f2bf(f.x); v.y=f2bf(f.y); v.z=f2bf(f.z); v.w=f2bf(f.w);
  *(ushort4*)&Wc[i4] = v;
}

__global__ __launch_bounds__(256) void transpose_cast(
    const float* __restrict__ src, unsigned short* __restrict__ dst, int R, int C)
{
  int i = blockIdx.x*256 + threadIdx.x;
  if (i >= R*C) return;
  int r = i / C, c = i - r*C;
  dst[c*R + r] = f2bf(src[i]);
}

// mean of two f32 planes -> bf16 [MROWP][KPAD]; one block per (row, batch).
__global__ __launch_bounds__(256) void mean_cast_row(
    const float* __restrict__ A0, const float* __restrict__ A1,
    unsigned short* __restrict__ D)
{
  int row = blockIdx.x;
  const float* p0 = (blockIdx.y ? A1 : A0) + (long long)row*N_NODES;
  const float* p1 = p0 + PLANE;
  unsigned short* d = D + (long long)blockIdx.y*ADJSTR + (long long)row*KPAD;

  for (int c = threadIdx.x*8; c < 7816; c += 2048) {
    float4 a0 = *(const float4*)(p0+c);
    float4 a1 = *(const float4*)(p0+c+4);
    float4 b0 = *(const float4*)(p1+c);
    float4 b1 = *(const float4*)(p1+c+4);
    float v[8] = {0.5f*(a0.x+b0.x), 0.5f*(a0.y+b0.y), 0.5f*(a0.z+b0.z), 0.5f*(a0.w+b0.w),
                  0.5f*(a1.x+b1.x), 0.5f*(a1.y+b1.y), 0.5f*(a1.z+b1.z), 0.5f*(a1.w+b1.w)};
    *(int4*)(d + c) = pack8(v);
  }
  int t = threadIdx.x;
  if (t < 7) {                      // cols 7816..7822
    int c = 7816 + t;
    d[c] = f2bf(0.5f*(p0[c] + p1[c]));
  }
}

// ---------------------------------------------------------------- spmm (counted-wait, 2 blocks/CU)
// parts[b][ks][m][n] = adjb[b][m][k] * BT[b][n][k] over k-chunk ks (2048 k).
// Block 128M x 128N, 8 waves (4M x 2N, each 32M x 64N, acc[2][4] = 32 AGPR).
// A: direct global->reg, 4-kt rolling prefetch; raw barriers never drain vmcnt.
// B: double-buffered LDS 2 x (128n x 128k = 32KB), XOR-swizzled; 2-kt subs.
// LDS 64KB + ~110 unified regs -> 2 blocks/CU: one block's barrier stall
// overlaps the other's MFMA (m114 TLP mechanism).
// Grid 992 = 8 (b,ks) groups x 124; XCD swizzle -> one (b,ks) per XCD.
__global__ __launch_bounds__(512, 4) void spmmK(
    const unsigned short* __restrict__ Abase,
    const unsigned short* __restrict__ Bbase,
    float* __restrict__ parts)
{
  __shared__ __align__(16) unsigned short Bs[2][128*128];  // 2 x 32 KB

  int bid = (blockIdx.x & 7)*124 + (blockIdx.x >> 3);
  int grp = bid / 124;             // 0..7 -> (b, ks)
  int q   = bid % 124;
  int b  = grp >> 2;
  int ks = grp & 3;
  int mt = q >> 1, nt = q & 1;

  const unsigned short* A  = Abase + b*ADJSTR;
  const unsigned short* BT = Bbase + b*BTSTR;
  int m0 = mt*128, n0 = nt*128;
  int kt0 = ks*32;                 // 32 kt of 64 k; 16 subs of 2 kt

  int tid = threadIdx.x, lane = tid & 63, w = tid >> 6;
  int wm = (w>>1)*32, wn = (w&1)*64;
  int grow = m0 + wm + (lane&15);
  long long rA0 = (long long)grow*KPAD + (lane>>4)*8;

  f32x4 acc[2][4] = {};

  int srow[4], sslot[4];
  #pragma unroll
  for (int i=0;i<4;i++){ int c = i*512 + tid; srow[i] = c>>4; sslot[i] = c&15; }

  int4 breg[4];
  auto loadB = [&](int sub){
    long long kb = (long long)kt0*64 + sub*128;
    #pragma unroll
    for (int i=0;i<4;i++)
      breg[i] = *(const int4*)(BT + (long long)(n0+srow[i])*KPAD + kb + sslot[i]*8);
  };
  auto storeB = [&](unsigned short* buf){
    #pragma unroll
    for (int i=0;i<4;i++)
      *(int4*)(buf + srow[i]*128 + (sslot[i]^(srow[i]&7))*8) = breg[i];
  };
  auto loadA = [&](int g, int4* a){
    const unsigned short* p = A + rA0 + (long long)g*64;
    a[0] = *(const int4*)(p);                // kk0 mf0
    a[1] = *(const int4*)(p + 16*KPAD);      // kk0 mf1
    a[2] = *(const int4*)(p + 32);           // kk1 mf0
    a[3] = *(const int4*)(p + 16*KPAD + 32); // kk1 mf1
  };
  auto compute = [&](int lt, const int4* a, const unsigned short* buf){
    #pragma unroll
    for (int kk=0; kk<2; ++kk) {
      short8 bv[4];
      #pragma unroll
      for (int nf=0; nf<4; ++nf) {
        int row = wn + nf*16 + (lane&15);
        int sl  = (lt*8 + kk*4 + (lane>>4)) ^ (lane&7);
        bv[nf] = *(const short8*)&buf[row*128 + sl*8];
      }
      #pragma unroll
      for (int mf=0; mf<2; ++mf) {
        short8 av = *(const short8*)&a[kk*2+mf];
        #pragma unroll
        for (int nf=0; nf<4; ++nf)
          acc[mf][nf] = __builtin_amdgcn_mfma_f32_16x16x32_bf16(av, bv[nf], acc[mf][nf], 0, 0, 0);
      }
    }
  };

  int gmax = kt0 + 31;
  int4 a0[4], a1[4], a2[4], a3[4];

  // prologue: stage sub 0, issue B[1] and A kt0..kt0+3
  loadB(0);
  loadA(kt0+0, a0);
  loadA(kt0+1, a1);
  loadA(kt0+2, a2);
  loadA(kt0+3, a3);
  storeB(&Bs[0][0]);               // counted wait for breg only
  loadB(1);
  asm volatile("s_waitcnt lgkmcnt(0)" ::: "memory");
  __builtin_amdgcn_s_barrier();
  __builtin_amdgcn_sched_barrier(0);

  int cur = 0;
  #pragma unroll 1
  for (int sp = 0; sp < 8; ++sp) {
    int g = kt0 + sp*4;
    {  // sub 2sp: kt g, g+1
      const unsigned short* Bc = &Bs[cur][0];
      compute(0, a0, Bc); loadA(min(g+4, gmax), a0);
      compute(1, a1, Bc); loadA(min(g+5, gmax), a1);
      __builtin_amdgcn_s_barrier();
      __builtin_amdgcn_sched_barrier(0);
      storeB(&Bs[cur^1][0]);
      loadB(min(2*sp+2, 15));
      asm volatile("s_waitcnt lgkmcnt(0)" ::: "memory");
      __builtin_amdgcn_s_barrier();
      __builtin_amdgcn_sched_barrier(0);
      cur ^= 1;
    }
    {  // sub 2sp+1: kt g+2, g+3
      const unsigned short* Bc = &Bs[cur][0];
      compute(0, a2, Bc); loadA(min(g+6, gmax), a2);
      compute(1, a3, Bc); loadA(min(g+7, gmax), a3);
      if (sp < 7) {
        __builtin_amdgcn_s_barrier();
        __builtin_amdgcn_sched_barrier(0);
        storeB(&Bs[cur^1][0]);
        loadB(min(2*sp+3, 15));
        asm volatile("s_waitcnt lgkmcnt(0)" ::: "memory");
        __builtin_amdgcn_s_barrier();
        __builtin_amdgcn_sched_barrier(0);
        cur ^= 1;
      }
    }
  }

  float* P = parts + b*PSTR + (long long)ks*NTOT;
  #pragma unroll
  for (int mf=0; mf<2; ++mf) {
    int mb = m0 + wm + mf*16 + ((lane>>4)<<2);
    #pragma unroll
    for (int i=0;i<4;i++){
      int m = mb + i;
      if (m < N_NODES) {
        #pragma unroll
        for (int nf=0; nf<4; ++nf) {
          int n = n0 + wn + nf*16 + (lane&15);
          P[(long long)m*256 + n] = acc[mf][nf][i];
        }
      }
    }
  }
}

// ---------------------------------------------------------------- batched small GEMM (bf16 A, transposed bf16 store)
#define BN 256
#define BK 64

__global__ __launch_bounds__(512, 4) void gemmS(
    const unsigned short* __restrict__ Abase, long long a_bstr, int lda,
    const unsigned short* __restrict__ Bbase, long long b_bstr, int ldb,
    int m_cnt, int tiles_m, int ktiles,
    unsigned short* __restrict__ CTb, long long ct_bstr, int ldct)
{
  __shared__ __align__(16) unsigned short As[64*BK];
  __shared__ __align__(16) unsigned short Bs[BN*BK];

  int bid = blockIdx.x;
  int b   = bid / tiles_m;
  int tm  = bid % tiles_m;

  const unsigned short* A  = Abase + b*a_bstr;
  const unsigned short* BT = Bbase + b*b_bstr;

  int m0 = tm*64;
  int tid = threadIdx.x;
  int lane = tid & 63, w = tid >> 6;
  int wm = (w >> 2)*32, wn = (w & 3)*64;

  f32x4 acc[2][4] = {};

  int arow, aslot, brow[4], bslot[4];
  { int c = tid; arow = c>>3; aslot = c&7; }
  #pragma unroll
  for (int i=0;i<4;i++){ int c = i*512 + tid; brow[i] = c>>3; bslot[i] = c&7; }

  int4 ra, rb[4];
  auto loadAB = [&](int kt){
    int gr = m0 + arow; if (gr > m_cnt-1) gr = m_cnt-1;
    ra = *(const int4*)(A + (long long)gr*lda + kt*BK + aslot*8);
    #pragma unroll
    for (int i=0;i<4;i++)
      rb[i] = *(const int4*)(BT + (long long)brow[i]*ldb + kt*BK + bslot[i]*8);
  };
  auto storeAB = [&](){
    *(int4*)(As + arow*BK + (aslot^(arow&7))*8) = ra;
    #pragma unroll
    for (int i=0;i<4;i++)
      *(int4*)(Bs + brow[i]*BK + (bslot[i]^(brow[i]&7))*8) = rb[i];
  };

  loadAB(0);
  for (int kt = 0; kt < ktiles; ++kt) {
    __syncthreads();
    storeAB();
    __syncthreads();
    if (kt+1 < ktiles) loadAB(kt+1);
    #pragma unroll
    for (int kk=0; kk<2; ++kk) {
      short8 av[2], bv[4];
      #pragma unroll
      for (int x=0;x<2;x++){
        int row = wm + x*16 + (lane&15);
        int slot = kk*4 + (lane>>4);
        av[x] = *(const short8*)&As[row*BK + (slot^(row&7))*8];
      }
      #pragma unroll
      for (int x=0;x<4;x++){
        int row = wn + x*16 + (lane&15);
        int slot = kk*4 + (lane>>4);
        bv[x] = *(const short8*)&Bs[row*BK + (slot^(row&7))*8];
      }
      #pragma unroll
      for (int mf=0; mf<2; ++mf)
        #pragma unroll
        for (int nf=0; nf<4; ++nf)
          acc[mf][nf] = __builtin_amdgcn_mfma_f32_16x16x32_bf16(av[mf], bv[nf], acc[mf][nf], 0, 0, 0);
    }
  }

  unsigned short* CT = CTb + b*ct_bstr;
  #pragma unroll
  for (int nf=0; nf<4; ++nf) {
    int n = wn + nf*16 + (lane&15);
    #pragma unroll
    for (int mf=0; mf<2; ++mf) {
      int mb = m0 + wm + mf*16 + ((lane>>4)<<2);
      ushort4 v;
      v.x = (mb+0 < m_cnt) ? f2bf(acc[mf][nf][0]) : (unsigned short)0;
      v.y = (mb+1 < m_cnt) ? f2bf(acc[mf][nf][1]) : (unsigned short)0;
      v.z = (mb+2 < m_cnt) ? f2bf(acc[mf][nf][2]) : (unsigned short)0;
      v.w = (mb+3 < m_cnt) ? f2bf(acc[mf][nf][3]) : (unsigned short)0;
      *(ushort4*)&CT[(long long)n*ldct + mb] = v;
    }
  }
}

// ---------------------------------------------------------------- adapter GEMM (grouped, f32 A)
__global__ __launch_bounds__(512, 4) void adapt_gemm(
    const float* __restrict__ f0, const float* __restrict__ f1, const float* __restrict__ f2,
    const unsigned short* __restrict__ Wc, float* __restrict__ C1)
{
  __shared__ __align__(16) unsigned short As[64*BK];
  __shared__ __align__(16) unsigned short Bs[BN*BK];

  int bid = blockIdx.x;
  int tn = bid & 3, tq = bid >> 2;
  int g, lt, m_cnt, gstart;
  if (tq < 12)      { g=0; lt=tq;    m_cnt=N_DRUG;           gstart=0; }
  else if (tq < 36) { g=1; lt=tq-12; m_cnt=N_TGT;            gstart=N_DRUG; }
  else              { g=2; lt=tq-36; m_cnt=N_NODES-N_D_T;    gstart=N_D_T; }
  const float* A = (g==0) ? f0 : (g==1) ? f1 : f2;
  const unsigned short* BT = Wc + (long long)g*1024*1024;

  int m0 = lt*64, n0 = tn*BN;
  int tid = threadIdx.x;
  int lane = tid & 63, w = tid >> 6;
  int wm = (w >> 2)*32, wn = (w & 3)*64;

  f32x4 acc[2][4] = {};

  int arow, aslot, brow[4], bslot[4];
  { int c = tid; arow = c>>3; aslot = c&7; }
  #pragma unroll
  for (int i=0;i<4;i++){ int c = i*512 + tid; brow[i] = c>>3; bslot[i] = c&7; }

  int4 ra, rb[4];
  auto loadAB = [&](int kt){
    int gr = m0 + arow; if (gr > m_cnt-1) gr = m_cnt-1;
    const float* p = A + (long long)gr*1024 + kt*BK + aslot*8;
    float4 q0 = *(const float4*)p;
    float4 q1 = *(const float4*)(p+4);
    float v[8] = {q0.x,q0.y,q0.z,q0.w,q1.x,q1.y,q1.z,q1.w};
    ra = pack8(v);
    #pragma unroll
    for (int i=0;i<4;i++)
      rb[i] = *(const int4*)(BT + (long long)(n0 + brow[i])*1024 + kt*BK + bslot[i]*8);
  };
  auto storeAB = [&](){
    *(int4*)(As + arow*BK + (aslot^(arow&7))*8) = ra;
    #pragma unroll
    for (int i=0;i<4;i++)
      *(int4*)(Bs + brow[i]*BK + (bslot[i]^(brow[i]&7))*8) = rb[i];
  };

  loadAB(0);
  for (int kt = 0; kt < 16; ++kt) {
    __syncthreads();
    storeAB();
    __syncthreads();
    if (kt+1 < 16) loadAB(kt+1);
    #pragma unroll
    for (int kk=0; kk<2; ++kk) {
      short8 av[2], bv[4];
      #pragma unroll
      for (int x=0;x<2;x++){
        int row = wm + x*16 + (lane&15);
        int slot = kk*4 + (lane>>4);
        av[x] = *(const short8*)&As[row*BK + (slot^(row&7))*8];
      }
      #pragma unroll
      for (int x=0;x<4;x++){
        int row = wn + x*16 + (lane&15);
        int slot = kk*4 + (lane>>4);
        bv[x] = *(const short8*)&Bs[row*BK + (slot^(row&7))*8];
      }
      #pragma unroll
      for (int mf=0; mf<2; ++mf)
        #pragma unroll
        for (int nf=0; nf<4; ++nf)
          acc[mf][nf] = __builtin_amdgcn_mfma_f32_16x16x32_bf16(av[mf], bv[nf], acc[mf][nf], 0, 0, 0);
    }
  }

  #pragma unroll
  for (int mf=0; mf<2; ++mf) {
    int mb = m0 + wm + mf*16 + ((lane>>4)<<2);
    #pragma unroll
    for (int i=0;i<4;i++){
      int m = mb + i;
      if (m < m_cnt) {
        #pragma unroll
        for (int nf=0; nf<4; ++nf) {
          int n = n0 + wn + nf*16 + (lane&15);
          C1[(long long)(gstart+m)*1024 + n] = acc[mf][nf][i];
        }
      }
    }
  }
}

// ---------------------------------------------------------------- fused epilogues

__global__ __launch_bounds__(256) void adapter_fuse(
    const float* __restrict__ C1,
    const float* __restrict__ b0, const float* __restrict__ g0, const float* __restrict__ be0, const float* __restrict__ br0,
    const float* __restrict__ b1, const float* __restrict__ g1, const float* __restrict__ be1, const float* __restrict__ br1,
    const float* __restrict__ b2, const float* __restrict__ g2, const float* __restrict__ be2, const float* __restrict__ br2,
    unsigned short* __restrict__ xall)
{
  int r = blockIdx.x;
  const float *b, *g, *be, *br;
  if (r < N_DRUG)     { b=b0; g=g0; be=be0; br=br0; }
  else if (r < N_D_T) { b=b1; g=g1; be=be1; br=br1; }
  else                { b=b2; g=g2; be=be2; br=br2; }
  int t = threadIdx.x;
  const float* row = C1 + (long long)r*1024;
  float ya = row[t]       + b[t];
  float yb = row[t + 256] + b[t + 256];
  float s = ya + yb, q = ya*ya + yb*yb;
  #pragma unroll
  for (int o=32;o;o>>=1){ s += __shfl_down(s,o); q += __shfl_down(q,o); }
  __shared__ float ss[4], qq[4];
  if ((t & 63) == 0) { ss[t>>6]=s; qq[t>>6]=q; }
  __syncthreads();
  float S = ss[0]+ss[1]+ss[2]+ss[3];
  float Q = qq[0]+qq[1]+qq[2]+qq[3];
  float mean = S * (1.f/512.f);
  float var  = Q * (1.f/512.f) - mean*mean;
  float inv  = rsqrtf(var + 1e-5f);
  float za = fmaxf((ya-mean)*inv*g[t]     + be[t],     0.f);
  float zb = fmaxf((yb-mean)*inv*g[t+256] + be[t+256], 0.f);
  float ha = za + row[512 + t] + br[t];
  float hb = zb + row[768 + t] + br[t + 256];
  ha = (ha > 0.f) ? ha : (expf(ha) - 1.f);
  hb = (hb > 0.f) ? hb : (expf(hb) - 1.f);
  xall[(long long)r*512 + t]       = f2bf(ha);
  xall[(long long)r*512 + t + 256] = f2bf(hb);
}

__global__ __launch_bounds__(256) void reduce_prelu2(
    const float* __restrict__ parts, const float* __restrict__ a0, const float* __restrict__ a1,
    unsigned short* __restrict__ h)
{
  int b = blockIdx.y;
  long long i = (long long)blockIdx.x*256 + threadIdx.x;
  const float* P = parts + b*PSTR;
  float s = 0.f;
  #pragma unroll
  for (int p=0;p<NSPLIT;p++) s += P[(long long)p*NTOT + i];
  float a = (b ? a1 : a0)[0];
  h[b*(long long)NTOT + i] = f2bf(s >= 0.f ? s : a*s);
}

__global__ __launch_bounds__(256) void reduce_stats2(
    const float* __restrict__ parts, float* __restrict__ Z, float* __restrict__ sp)
{
  int b = blockIdx.y;
  long long i = (long long)blockIdx.x*256 + threadIdx.x;
  const float* P = parts + b*PSTR;
  float s = 0.f;
  #pragma unroll
  for (int p=0;p<NSPLIT;p++) s += P[(long long)p*NTOT + i];
  Z[b*(long long)NTOT + i] = s;
  float a = s, q = s*s;
  #pragma unroll
  for (int o=32;o;o>>=1){ a += __shfl_down(a,o); q += __shfl_down(q,o); }
  __shared__ float ss[4], qq[4];
  int t = threadIdx.x;
  if ((t&63)==0){ ss[t>>6]=a; qq[t>>6]=q; }
  __syncthreads();
  if (t==0) {
    sp[(long long)b*2*N_NODES + 2*blockIdx.x]   = ss[0]+ss[1]+ss[2]+ss[3];
    sp[(long long)b*2*N_NODES + 2*blockIdx.x+1] = qq[0]+qq[1]+qq[2]+qq[3];
  }
}

__global__ __launch_bounds__(256) void stats_final2(
    const float* __restrict__ sp, float* __restrict__ stats)
{
  int b = blockIdx.x;
  const float* S = sp + (long long)b*2*N_NODES;
  int t = threadIdx.x;
  float s = 0.f, q = 0.f;
  for (int i=t; i<N_NODES; i+=256){ s += S[2*i]; q += S[2*i+1]; }
  #pragma unroll
  for (int o=32;o;o>>=1){ s += __shfl_down(s,o); q += __shfl_down(q,o); }
  __shared__ float ss[4], qq[4];
  if ((t&63)==0){ ss[t>>6]=s; qq[t>>6]=q; }
  __syncthreads();
  if (t==0){ stats[b*16]=ss[0]+ss[1]+ss[2]+ss[3]; stats[b*16+1]=qq[0]+qq[1]+qq[2]+qq[3]; }
}

__global__ __launch_bounds__(256) void finalize(
    const float* __restrict__ Z, const float* __restrict__ stats,
    float* __restrict__ out, int row_lo, long long out_off)
{
  int r = row_lo + blockIdx.x;
  int t = threadIdx.x;
  float mean = stats[0] * (1.f/(float)NTOT);
  float var  = stats[1] * (1.f/(float)NTOT) - mean*mean;
  float inv  = rsqrtf(var + 1e-5f);
  float z = (Z[(long long)r*256 + t] - mean) * inv;
  float q = z*z;
  #pragma unroll
  for (int o=32;o;o>>=1) q += __shfl_down(q,o);
  __shared__ float qq[4];
  if ((t&63)==0) qq[t>>6]=q;
  __syncthreads();
  float norm = sqrtf(qq[0]+qq[1]+qq[2]+qq[3]);
  out[out_off + (long long)blockIdx.x*256 + t] = z / (norm + 1e-8f);
}

// ---------------------------------------------------------------- launcher

extern "C" void kernel_launch(void* const* d_in, const int* in_sizes, int n_in,
                              void* d_out, int out_size, void* d_ws, size_t ws_size,
                              hipStream_t stream)
{
  const float* drug_feats    = (const float*)d_in[0];
  const float* target_feats  = (const float*)d_in[1];
  const float* disease_feats = (const float*)d_in[2];
  const float* drug_adjs     = (const float*)d_in[3];
  const float* target_adjs   = (const float*)d_in[4];
  const float* dA_W  = (const float*)d_in[5];
  const float* dA_b  = (const float*)d_in[6];
  const float* dA_g  = (const float*)d_in[7];
  const float* dA_be = (const float*)d_in[8];
  const float* dA_Wr = (const float*)d_in[9];
  const float* dA_br = (const float*)d_in[10];
  const float* tA_W  = (const float*)d_in[11];
  const float* tA_b  = (const float*)d_in[12];
  const float* tA_g  = (const float*)d_in[13];
  const float* tA_be = (const float*)d_in[14];
  const float* tA_Wr = (const float*)d_in[15];
  const float* tA_br = (const float*)d_in[16];
  const float* sA_W  = (const float*)d_in[17];
  const float* sA_b  = (const float*)d_in[18];
  const float* sA_g  = (const float*)d_in[19];
  const float* sA_be = (const float*)d_in[20];
  const float* sA_Wr = (const float*)d_in[21];
  const float* sA_br = (const float*)d_in[22];
  const float* dG_W1 = (const float*)d_in[23];
  const float* dG_W2 = (const float*)d_in[24];
  const float* tG_W1 = (const float*)d_in[25];
  const float* tG_W2 = (const float*)d_in[26];
  const float* dG_a  = (const float*)d_in[27];
  const float* tG_a  = (const float*)d_in[28];

  char* ws = (char*)d_ws;
  size_t off = 0;
  auto alloc = [&](size_t bytes)->void* {
    void* p = ws + off;
    off += (bytes + 255) & ~(size_t)255;
    return p;
  };

  unsigned short* Wc   = (unsigned short*)alloc((size_t)3*1024*1024*2);
  unsigned short* W1T  = (unsigned short*)alloc((size_t)2*256*512*2);
  unsigned short* W2T  = (unsigned short*)alloc((size_t)2*256*256*2);
  unsigned short* xall = (unsigned short*)alloc((size_t)N_NODES*512*2);
  unsigned short* adjb = (unsigned short*)alloc((size_t)2*ADJSTR*2);
  unsigned short* xw1T = (unsigned short*)alloc((size_t)2*BTSTR*2);
  unsigned short* hbuf = (unsigned short*)alloc((size_t)2*NTOT*2);
  unsigned short* hw2T = (unsigned short*)alloc((size_t)2*BTSTR*2);
  float* parts = (float*)alloc((size_t)2*PSTR*4);      // aliased as C1 (64 MB)
  float* Zf    = (float*)alloc((size_t)2*NTOT*4);
  float* spart = (float*)alloc((size_t)2*N_NODES*2*4);
  float* stats = (float*)alloc((size_t)32*4);
  float* C1    = parts;
  float* outp  = (float*)d_out;

  // weight casts
  cast_wc<<<3072, 256, 0, stream>>>(dA_W, dA_Wr, tA_W, tA_Wr, sA_W, sA_Wr, Wc);
  transpose_cast<<<512, 256, 0, stream>>>(dG_W1, W1T,            512, 256);
  transpose_cast<<<512, 256, 0, stream>>>(tG_W1, W1T + 256*512,  512, 256);
  transpose_cast<<<256, 256, 0, stream>>>(dG_W2, W2T,            256, 256);
  transpose_cast<<<256, 256, 0, stream>>>(tG_W2, W2T + 256*256,  256, 256);

  // adapters (one grouped dispatch) then fuse
  adapt_gemm<<<496, 512, 0, stream>>>(drug_feats, target_feats, disease_feats, Wc, C1);
  adapter_fuse<<<N_NODES, 256, 0, stream>>>(C1,
      dA_b, dA_g, dA_be, dA_br,
      tA_b, tA_g, tA_be, tA_br,
      sA_b, sA_g, sA_be, sA_br, xall);

  // xw1T[b][n][node] = (x_all @ W1_b)^T, bf16, zero-filled nodes 7823..8191
  gemmS<<<2*128, 512, 0, stream>>>(
      xall, 0, 512, W1T, 256*512, 512,
      N_NODES, 128, 8, xw1T, BTSTR, KPAD);

  // mean+cast both adjs (real cols only; pads never contribute)
  mean_cast_row<<<dim3(N_NODES, 2), 256, 0, stream>>>(drug_adjs, target_adjs, adjb);

  // spmm1: parts[b][ks] = adjb[b] @ xw1[b]   (992 blocks, 2/CU)
  spmmK<<<992, 512, 0, stream>>>(adjb, xw1T, parts);

  reduce_prelu2<<<dim3(N_NODES,2), 256, 0, stream>>>(parts, dG_a, tG_a, hbuf);

  // hw2T[b][n][node] = (h_b @ W2_b)^T
  gemmS<<<2*128, 512, 0, stream>>>(
      hbuf, (long long)NTOT, 256, W2T, 256*256, 256,
      N_NODES, 128, 4, hw2T, BTSTR, KPAD);

  // spmm2: parts[b][ks] = adjb[b] @ hw2[b]
  spmmK<<<992, 512, 0, stream>>>(adjb, hw2T, parts);

  reduce_stats2<<<dim3(N_NODES,2), 256, 0, stream>>>(parts, Zf, spart);
  stats_final2<<<2, 256, 0, stream>>>(spart, stats);

  finalize<<<N_DRUG, 256, 0, stream>>>(Zf, stats, outp, 0, 0LL);
  finalize<<<N_TGT, 256, 0, stream>>>(Zf + NTOT, stats + 16, outp, N_DRUG, (long long)N_DRUG*256);
}

// Round 14
// 842.653 us; speedup vs baseline: 1.4559x; 1.4559x over previous
//
#include <hip/hip_runtime.h>
#include <hip/hip_bf16.h>
#include <stdint.h>

typedef __attribute__((ext_vector_type(8))) short short8;
typedef __attribute__((ext_vector_type(4))) float f32x4;

#define N_DRUG 708
#define N_TGT  1512
#define N_NODES 7823
#define N_D_T  2220          // 708+1512
#define KPAD   8192          // 128 * 64
#define MROWP  7936          // 31 * 256 (adjb row pad)
#define NTOT   2002688       // 7823*256
#define NSPLIT 4
#define PLANE  61199329LL    // 7823*7823
#define ADJSTR ((long long)MROWP*KPAD)     // adjb batch stride (elems)
#define BTSTR  ((long long)256*KPAD)       // xw1T/hw2T batch stride
#define PSTR   ((long long)NSPLIT*NTOT)    // parts batch stride

__device__ __forceinline__ unsigned short f2bf(float f) {
  union { float f; unsigned int i; } v; v.f = f;
  unsigned int r = v.i + 0x7FFF + ((v.i >> 16) & 1);
  return (unsigned short)(r >> 16);
}

__device__ __forceinline__ int4 pack8(const float v[8]) {
  union { int4 i4; unsigned short u[8]; } r;
  #pragma unroll
  for (int j = 0; j < 8; j++) r.u[j] = f2bf(v[j]);
  return r.i4;
}

// ---------------------------------------------------------------- cast kernels

__global__ __launch_bounds__(256) void cast_wc(
    const float* __restrict__ w0, const float* __restrict__ wr0,
    const float* __restrict__ w1, const float* __restrict__ wr1,
    const float* __restrict__ w2, const float* __restrict__ wr2,
    unsigned short* __restrict__ Wc)
{
  long long i4 = ((long long)blockIdx.x*256 + threadIdx.x)*4;
  int g  = (int)(i4 >> 20);
  int rr = (int)((i4 >> 10) & 1023);
  int c  = (int)(i4 & 1023);
  const float* src = (g==0) ? (rr<512?w0:wr0) : (g==1) ? (rr<512?w1:wr1) : (rr<512?w2:wr2);
  float4 f = *(const float4*)(src + (long long)(rr & 511)*1024 + c);
  ushort4 v; v.x=f2bf(f.x); v.y=f2bf(f.y); v.z=f2bf(f.z); v.w=f2bf(f.w);
  *(ushort4*)&Wc[i4] = v;
}

__global__ __launch_bounds__(256) void transpose_cast(
    const float* __restrict__ src, unsigned short* __restrict__ dst, int R, int C)
{
  int i = blockIdx.x*256 + threadIdx.x;
  if (i >= R*C) return;
  int r = i / C, c = i - r*C;
  dst[c*R + r] = f2bf(src[i]);
}

// mean of two f32 planes -> bf16 [MROWP][KPAD]; one block per (row, batch).
// No divides; aligned int4 stores. Pad cols/rows NOT written (B side is zeroed
// there; pad rows are discarded at the spmm C-store; 0xAA bf16 is finite).
__global__ __launch_bounds__(256) void mean_cast_row(
    const float* __restrict__ A0, const float* __restrict__ A1,
    unsigned short* __restrict__ D)
{
  int row = blockIdx.x;
  const float* p0 = (blockIdx.y ? A1 : A0) + (long long)row*N_NODES;
  const float* p1 = p0 + PLANE;
  unsigned short* d = D + (long long)blockIdx.y*ADJSTR + (long long)row*KPAD;

  for (int c = threadIdx.x*8; c < 7816; c += 2048) {
    float4 a0 = *(const float4*)(p0+c);
    float4 a1 = *(const float4*)(p0+c+4);
    float4 b0 = *(const float4*)(p1+c);
    float4 b1 = *(const float4*)(p1+c+4);
    float v[8] = {0.5f*(a0.x+b0.x), 0.5f*(a0.y+b0.y), 0.5f*(a0.z+b0.z), 0.5f*(a0.w+b0.w),
                  0.5f*(a1.x+b1.x), 0.5f*(a1.y+b1.y), 0.5f*(a1.z+b1.z), 0.5f*(a1.w+b1.w)};
    *(int4*)(d + c) = pack8(v);
  }
  int t = threadIdx.x;
  if (t < 7) {                      // cols 7816..7822
    int c = 7816 + t;
    d[c] = f2bf(0.5f*(p0[c] + p1[c]));
  }
}

// ---------------------------------------------------------------- spmm (counted-wait pipeline)
// parts[b][ks][m][n] = adjb[b][m][k] * BT[b][n][k] over k-chunk ks (2048 k).
// Block 256M x 128N, 8 waves (each 32M x 128N, acc[2][8]).
// A: direct global->reg, 4-kt-deep rolling prefetch (never drained: raw barriers).
// B: double-buffered LDS 2 x (128n x 256k = 64KB), XOR-swizzled; regs for sub+1
//    in flight across barriers; compiler inserts counted vmcnt before ds_write.
// Grid 496 = 8 (b,ks) groups x 62; XCD swizzle -> one (b,ks) per XCD.
__global__ __launch_bounds__(512, 2) void spmmK(
    const unsigned short* __restrict__ Abase,
    const unsigned short* __restrict__ Bbase,
    float* __restrict__ parts)
{
  __shared__ __align__(16) unsigned short Bs[2][128*256];  // 2 x 64 KB

  int bid = (blockIdx.x & 7)*62 + (blockIdx.x >> 3);
  int grp = bid / 62;              // 0..7 -> (b, ks)
  int q   = bid % 62;
  int b  = grp >> 2;
  int ks = grp & 3;
  int mt = q >> 1, nt = q & 1;

  const unsigned short* A  = Abase + b*ADJSTR;
  const unsigned short* BT = Bbase + b*BTSTR;
  int m0 = mt*256, n0 = nt*128;
  int kt0 = ks*32;                 // 32 kt of 64 k; 8 subs of 4 kt

  int tid = threadIdx.x, lane = tid & 63, w = tid >> 6;
  int grow = m0 + w*32 + (lane&15);
  long long rA0 = (long long)grow*KPAD + (lane>>4)*8;

  f32x4 acc[2][8] = {};

  int srow[8], sslot[8];
  #pragma unroll
  for (int i=0;i<8;i++){ int c = i*512 + tid; srow[i] = c>>5; sslot[i] = c&31; }

  int4 breg[8];
  auto loadB = [&](int sub){
    long long kb = (long long)kt0*64 + sub*256;
    #pragma unroll
    for (int i=0;i<8;i++)
      breg[i] = *(const int4*)(BT + (long long)(n0+srow[i])*KPAD + kb + sslot[i]*8);
  };
  auto storeB = [&](unsigned short* buf){
    #pragma unroll
    for (int i=0;i<8;i++)
      *(int4*)(buf + srow[i]*256 + (sslot[i]^(srow[i]&7))*8) = breg[i];
  };
  auto loadA = [&](int g, int4* a){
    const unsigned short* p = A + rA0 + (long long)g*64;
    a[0] = *(const int4*)(p);
    a[1] = *(const int4*)(p + 16*KPAD);
    a[2] = *(const int4*)(p + 32);
    a[3] = *(const int4*)(p + 16*KPAD + 32);
  };
  auto compute = [&](int lt, const int4* a, const unsigned short* buf){
    #pragma unroll
    for (int kk=0; kk<2; ++kk) {
      short8 bv[8];
      #pragma unroll
      for (int nf=0; nf<8; ++nf) {
        int row = nf*16 + (lane&15);
        int sl  = (lt*8 + kk*4 + (lane>>4)) ^ (lane&7);
        bv[nf] = *(const short8*)&buf[row*256 + sl*8];
      }
      #pragma unroll
      for (int mf=0; mf<2; ++mf) {
        short8 av = *(const short8*)&a[kk*2+mf];
        #pragma unroll
        for (int nf=0; nf<8; ++nf)
          acc[mf][nf] = __builtin_amdgcn_mfma_f32_16x16x32_bf16(av, bv[nf], acc[mf][nf], 0, 0, 0);
      }
    }
  };

  int gmax = kt0 + 31;
  int4 a0[4], a1[4], a2[4], a3[4];

  // prologue: stage sub 0, issue B[1] and A[kt0..kt0+3]
  loadB(0);
  loadA(kt0+0, a0);
  loadA(kt0+1, a1);
  loadA(kt0+2, a2);
  loadA(kt0+3, a3);
  storeB(&Bs[0][0]);               // compiler waits (counted) for breg only
  loadB(1);
  asm volatile("s_waitcnt lgkmcnt(0)" ::: "memory");
  __builtin_amdgcn_s_barrier();
  __builtin_amdgcn_sched_barrier(0);

  int cur = 0;
  for (int sub = 0; sub < 8; ++sub) {
    const unsigned short* Bc = &Bs[cur][0];
    int g = kt0 + sub*4;
    compute(0, a0, Bc); loadA(min(g+4, gmax), a0);
    compute(1, a1, Bc); loadA(min(g+5, gmax), a1);
    compute(2, a2, Bc); loadA(min(g+6, gmax), a2);
    compute(3, a3, Bc); loadA(min(g+7, gmax), a3);
    if (sub < 7) {
      __builtin_amdgcn_s_barrier();          // all waves done reading Bs[cur^1]
      __builtin_amdgcn_sched_barrier(0);
      storeB(&Bs[cur^1][0]);                 // counted vmcnt for breg
      loadB(min(sub+2, 7));
      asm volatile("s_waitcnt lgkmcnt(0)" ::: "memory");
      __builtin_amdgcn_s_barrier();          // Bs[cur^1] visible to all
      __builtin_amdgcn_sched_barrier(0);
      cur ^= 1;
    }
  }

  float* P = parts + b*PSTR + (long long)ks*NTOT;
  #pragma unroll
  for (int mf=0; mf<2; ++mf) {
    int mb = m0 + w*32 + mf*16 + ((lane>>4)<<2);
    #pragma unroll
    for (int i=0;i<4;i++){
      int m = mb + i;
      if (m < N_NODES) {
        #pragma unroll
        for (int nf=0; nf<8; ++nf) {
          int n = n0 + nf*16 + (lane&15);
          P[(long long)m*256 + n] = acc[mf][nf][i];
        }
      }
    }
  }
}

// ---------------------------------------------------------------- batched small GEMM (bf16 A, transposed bf16 store)
#define BN 256
#define BK 64

__global__ __launch_bounds__(512, 4) void gemmS(
    const unsigned short* __restrict__ Abase, long long a_bstr, int lda,
    const unsigned short* __restrict__ Bbase, long long b_bstr, int ldb,
    int m_cnt, int tiles_m, int ktiles,
    unsigned short* __restrict__ CTb, long long ct_bstr, int ldct)
{
  __shared__ __align__(16) unsigned short As[64*BK];
  __shared__ __align__(16) unsigned short Bs[BN*BK];

  int bid = blockIdx.x;
  int b   = bid / tiles_m;
  int tm  = bid % tiles_m;

  const unsigned short* A  = Abase + b*a_bstr;
  const unsigned short* BT = Bbase + b*b_bstr;

  int m0 = tm*64;
  int tid = threadIdx.x;
  int lane = tid & 63, w = tid >> 6;
  int wm = (w >> 2)*32, wn = (w & 3)*64;

  f32x4 acc[2][4] = {};

  int arow, aslot, brow[4], bslot[4];
  { int c = tid; arow = c>>3; aslot = c&7; }
  #pragma unroll
  for (int i=0;i<4;i++){ int c = i*512 + tid; brow[i] = c>>3; bslot[i] = c&7; }

  int4 ra, rb[4];
  auto loadAB = [&](int kt){
    int gr = m0 + arow; if (gr > m_cnt-1) gr = m_cnt-1;
    ra = *(const int4*)(A + (long long)gr*lda + kt*BK + aslot*8);
    #pragma unroll
    for (int i=0;i<4;i++)
      rb[i] = *(const int4*)(BT + (long long)brow[i]*ldb + kt*BK + bslot[i]*8);
  };
  auto storeAB = [&](){
    *(int4*)(As + arow*BK + (aslot^(arow&7))*8) = ra;
    #pragma unroll
    for (int i=0;i<4;i++)
      *(int4*)(Bs + brow[i]*BK + (bslot[i]^(brow[i]&7))*8) = rb[i];
  };

  loadAB(0);
  for (int kt = 0; kt < ktiles; ++kt) {
    __syncthreads();
    storeAB();
    __syncthreads();
    if (kt+1 < ktiles) loadAB(kt+1);
    #pragma unroll
    for (int kk=0; kk<2; ++kk) {
      short8 av[2], bv[4];
      #pragma unroll
      for (int x=0;x<2;x++){
        int row = wm + x*16 + (lane&15);
        int slot = kk*4 + (lane>>4);
        av[x] = *(const short8*)&As[row*BK + (slot^(row&7))*8];
      }
      #pragma unroll
      for (int x=0;x<4;x++){
        int row = wn + x*16 + (lane&15);
        int slot = kk*4 + (lane>>4);
        bv[x] = *(const short8*)&Bs[row*BK + (slot^(row&7))*8];
      }
      #pragma unroll
      for (int mf=0; mf<2; ++mf)
        #pragma unroll
        for (int nf=0; nf<4; ++nf)
          acc[mf][nf] = __builtin_amdgcn_mfma_f32_16x16x32_bf16(av[mf], bv[nf], acc[mf][nf], 0, 0, 0);
    }
  }

  unsigned short* CT = CTb + b*ct_bstr;
  #pragma unroll
  for (int nf=0; nf<4; ++nf) {
    int n = wn + nf*16 + (lane&15);
    #pragma unroll
    for (int mf=0; mf<2; ++mf) {
      int mb = m0 + wm + mf*16 + ((lane>>4)<<2);
      ushort4 v;
      v.x = (mb+0 < m_cnt) ? f2bf(acc[mf][nf][0]) : (unsigned short)0;
      v.y = (mb+1 < m_cnt) ? f2bf(acc[mf][nf][1]) : (unsigned short)0;
      v.z = (mb+2 < m_cnt) ? f2bf(acc[mf][nf][2]) : (unsigned short)0;
      v.w = (mb+3 < m_cnt) ? f2bf(acc[mf][nf][3]) : (unsigned short)0;
      *(ushort4*)&CT[(long long)n*ldct + mb] = v;
    }
  }
}

// ---------------------------------------------------------------- adapter GEMM (grouped, f32 A)
__global__ __launch_bounds__(512, 4) void adapt_gemm(
    const float* __restrict__ f0, const float* __restrict__ f1, const float* __restrict__ f2,
    const unsigned short* __restrict__ Wc, float* __restrict__ C1)
{
  __shared__ __align__(16) unsigned short As[64*BK];
  __shared__ __align__(16) unsigned short Bs[BN*BK];

  int bid = blockIdx.x;
  int tn = bid & 3, tq = bid >> 2;
  int g, lt, m_cnt, gstart;
  if (tq < 12)      { g=0; lt=tq;    m_cnt=N_DRUG;           gstart=0; }
  else if (tq < 36) { g=1; lt=tq-12; m_cnt=N_TGT;            gstart=N_DRUG; }
  else              { g=2; lt=tq-36; m_cnt=N_NODES-N_D_T;    gstart=N_D_T; }
  const float* A = (g==0) ? f0 : (g==1) ? f1 : f2;
  const unsigned short* BT = Wc + (long long)g*1024*1024;

  int m0 = lt*64, n0 = tn*BN;
  int tid = threadIdx.x;
  int lane = tid & 63, w = tid >> 6;
  int wm = (w >> 2)*32, wn = (w & 3)*64;

  f32x4 acc[2][4] = {};

  int arow, aslot, brow[4], bslot[4];
  { int c = tid; arow = c>>3; aslot = c&7; }
  #pragma unroll
  for (int i=0;i<4;i++){ int c = i*512 + tid; brow[i] = c>>3; bslot[i] = c&7; }

  int4 ra, rb[4];
  auto loadAB = [&](int kt){
    int gr = m0 + arow; if (gr > m_cnt-1) gr = m_cnt-1;
    const float* p = A + (long long)gr*1024 + kt*BK + aslot*8;
    float4 q0 = *(const float4*)p;
    float4 q1 = *(const float4*)(p+4);
    float v[8] = {q0.x,q0.y,q0.z,q0.w,q1.x,q1.y,q1.z,q1.w};
    ra = pack8(v);
    #pragma unroll
    for (int i=0;i<4;i++)
      rb[i] = *(const int4*)(BT + (long long)(n0 + brow[i])*1024 + kt*BK + bslot[i]*8);
  };
  auto storeAB = [&](){
    *(int4*)(As + arow*BK + (aslot^(arow&7))*8) = ra;
    #pragma unroll
    for (int i=0;i<4;i++)
      *(int4*)(Bs + brow[i]*BK + (bslot[i]^(brow[i]&7))*8) = rb[i];
  };

  loadAB(0);
  for (int kt = 0; kt < 16; ++kt) {
    __syncthreads();
    storeAB();
    __syncthreads();
    if (kt+1 < 16) loadAB(kt+1);
    #pragma unroll
    for (int kk=0; kk<2; ++kk) {
      short8 av[2], bv[4];
      #pragma unroll
      for (int x=0;x<2;x++){
        int row = wm + x*16 + (lane&15);
        int slot = kk*4 + (lane>>4);
        av[x] = *(const short8*)&As[row*BK + (slot^(row&7))*8];
      }
      #pragma unroll
      for (int x=0;x<4;x++){
        int row = wn + x*16 + (lane&15);
        int slot = kk*4 + (lane>>4);
        bv[x] = *(const short8*)&Bs[row*BK + (slot^(row&7))*8];
      }
      #pragma unroll
      for (int mf=0; mf<2; ++mf)
        #pragma unroll
        for (int nf=0; nf<4; ++nf)
          acc[mf][nf] = __builtin_amdgcn_mfma_f32_16x16x32_bf16(av[mf], bv[nf], acc[mf][nf], 0, 0, 0);
    }
  }

  #pragma unroll
  for (int mf=0; mf<2; ++mf) {
    int mb = m0 + wm + mf*16 + ((lane>>4)<<2);
    #pragma unroll
    for (int i=0;i<4;i++){
      int m = mb + i;
      if (m < m_cnt) {
        #pragma unroll
        for (int nf=0; nf<4; ++nf) {
          int n = n0 + wn + nf*16 + (lane&15);
          C1[(long long)(gstart+m)*1024 + n] = acc[mf][nf][i];
        }
      }
    }
  }
}

// ---------------------------------------------------------------- fused epilogues

__global__ __launch_bounds__(256) void adapter_fuse(
    const float* __restrict__ C1,
    const float* __restrict__ b0, const float* __restrict__ g0, const float* __restrict__ be0, const float* __restrict__ br0,
    const float* __restrict__ b1, const float* __restrict__ g1, const float* __restrict__ be1, const float* __restrict__ br1,
    const float* __restrict__ b2, const float* __restrict__ g2, const float* __restrict__ be2, const float* __restrict__ br2,
    unsigned short* __restrict__ xall)
{
  int r = blockIdx.x;
  const float *b, *g, *be, *br;
  if (r < N_DRUG)     { b=b0; g=g0; be=be0; br=br0; }
  else if (r < N_D_T) { b=b1; g=g1; be=be1; br=br1; }
  else                { b=b2; g=g2; be=be2; br=br2; }
  int t = threadIdx.x;
  const float* row = C1 + (long long)r*1024;
  float ya = row[t]       + b[t];
  float yb = row[t + 256] + b[t + 256];
  float s = ya + yb, q = ya*ya + yb*yb;
  #pragma unroll
  for (int o=32;o;o>>=1){ s += __shfl_down(s,o); q += __shfl_down(q,o); }
  __shared__ float ss[4], qq[4];
  if ((t & 63) == 0) { ss[t>>6]=s; qq[t>>6]=q; }
  __syncthreads();
  float S = ss[0]+ss[1]+ss[2]+ss[3];
  float Q = qq[0]+qq[1]+qq[2]+qq[3];
  float mean = S * (1.f/512.f);
  float var  = Q * (1.f/512.f) - mean*mean;
  float inv  = rsqrtf(var + 1e-5f);
  float za = fmaxf((ya-mean)*inv*g[t]     + be[t],     0.f);
  float zb = fmaxf((yb-mean)*inv*g[t+256] + be[t+256], 0.f);
  float ha = za + row[512 + t] + br[t];
  float hb = zb + row[768 + t] + br[t + 256];
  ha = (ha > 0.f) ? ha : (expf(ha) - 1.f);
  hb = (hb > 0.f) ? hb : (expf(hb) - 1.f);
  xall[(long long)r*512 + t]       = f2bf(ha);
  xall[(long long)r*512 + t + 256] = f2bf(hb);
}

__global__ __launch_bounds__(256) void reduce_prelu2(
    const float* __restrict__ parts, const float* __restrict__ a0, const float* __restrict__ a1,
    unsigned short* __restrict__ h)
{
  int b = blockIdx.y;
  long long i = (long long)blockIdx.x*256 + threadIdx.x;
  const float* P = parts + b*PSTR;
  float s = 0.f;
  #pragma unroll
  for (int p=0;p<NSPLIT;p++) s += P[(long long)p*NTOT + i];
  float a = (b ? a1 : a0)[0];
  h[b*(long long)NTOT + i] = f2bf(s >= 0.f ? s : a*s);
}

__global__ __launch_bounds__(256) void reduce_stats2(
    const float* __restrict__ parts, float* __restrict__ Z, float* __restrict__ sp)
{
  int b = blockIdx.y;
  long long i = (long long)blockIdx.x*256 + threadIdx.x;
  const float* P = parts + b*PSTR;
  float s = 0.f;
  #pragma unroll
  for (int p=0;p<NSPLIT;p++) s += P[(long long)p*NTOT + i];
  Z[b*(long long)NTOT + i] = s;
  float a = s, q = s*s;
  #pragma unroll
  for (int o=32;o;o>>=1){ a += __shfl_down(a,o); q += __shfl_down(q,o); }
  __shared__ float ss[4], qq[4];
  int t = threadIdx.x;
  if ((t&63)==0){ ss[t>>6]=a; qq[t>>6]=q; }
  __syncthreads();
  if (t==0) {
    sp[(long long)b*2*N_NODES + 2*blockIdx.x]   = ss[0]+ss[1]+ss[2]+ss[3];
    sp[(long long)b*2*N_NODES + 2*blockIdx.x+1] = qq[0]+qq[1]+qq[2]+qq[3];
  }
}

__global__ __launch_bounds__(256) void stats_final2(
    const float* __restrict__ sp, float* __restrict__ stats)
{
  int b = blockIdx.x;
  const float* S = sp + (long long)b*2*N_NODES;
  int t = threadIdx.x;
  float s = 0.f, q = 0.f;
  for (int i=t; i<N_NODES; i+=256){ s += S[2*i]; q += S[2*i+1]; }
  #pragma unroll
  for (int o=32;o;o>>=1){ s += __shfl_down(s,o); q += __shfl_down(q,o); }
  __shared__ float ss[4], qq[4];
  if ((t&63)==0){ ss[t>>6]=s; qq[t>>6]=q; }
  __syncthreads();
  if (t==0){ stats[b*16]=ss[0]+ss[1]+ss[2]+ss[3]; stats[b*16+1]=qq[0]+qq[1]+qq[2]+qq[3]; }
}

__global__ __launch_bounds__(256) void finalize(
    const float* __restrict__ Z, const float* __restrict__ stats,
    float* __restrict__ out, int row_lo, long long out_off)
{
  int r = row_lo + blockIdx.x;
  int t = threadIdx.x;
  float mean = stats[0] * (1.f/(float)NTOT);
  float var  = stats[1] * (1.f/(float)NTOT) - mean*mean;
  float inv  = rsqrtf(var + 1e-5f);
  float z = (Z[(long long)r*256 + t] - mean) * inv;
  float q = z*z;
  #pragma unroll
  for (int o=32;o;o>>=1) q += __shfl_down(q,o);
  __shared__ float qq[4];
  if ((t&63)==0) qq[t>>6]=q;
  __syncthreads();
  float norm = sqrtf(qq[0]+qq[1]+qq[2]+qq[3]);
  out[out_off + (long long)blockIdx.x*256 + t] = z / (norm + 1e-8f);
}

// ---------------------------------------------------------------- launcher

extern "C" void kernel_launch(void* const* d_in, const int* in_sizes, int n_in,
                              void* d_out, int out_size, void* d_ws, size_t ws_size,
                              hipStream_t stream)
{
  const float* drug_feats    = (const float*)d_in[0];
  const float* target_feats  = (const float*)d_in[1];
  const float* disease_feats = (const float*)d_in[2];
  const float* drug_adjs     = (const float*)d_in[3];
  const float* target_adjs   = (const float*)d_in[4];
  const float* dA_W  = (const float*)d_in[5];
  const float* dA_b  = (const float*)d_in[6];
  const float* dA_g  = (const float*)d_in[7];
  const float* dA_be = (const float*)d_in[8];
  const float* dA_Wr = (const float*)d_in[9];
  const float* dA_br = (const float*)d_in[10];
  const float* tA_W  = (const float*)d_in[11];
  const float* tA_b  = (const float*)d_in[12];
  const float* tA_g  = (const float*)d_in[13];
  const float* tA_be = (const float*)d_in[14];
  const float* tA_Wr = (const float*)d_in[15];
  const float* tA_br = (const float*)d_in[16];
  const float* sA_W  = (const float*)d_in[17];
  const float* sA_b  = (const float*)d_in[18];
  const float* sA_g  = (const float*)d_in[19];
  const float* sA_be = (const float*)d_in[20];
  const float* sA_Wr = (const float*)d_in[21];
  const float* sA_br = (const float*)d_in[22];
  const float* dG_W1 = (const float*)d_in[23];
  const float* dG_W2 = (const float*)d_in[24];
  const float* tG_W1 = (const float*)d_in[25];
  const float* tG_W2 = (const float*)d_in[26];
  const float* dG_a  = (const float*)d_in[27];
  const float* tG_a  = (const float*)d_in[28];

  char* ws = (char*)d_ws;
  size_t off = 0;
  auto alloc = [&](size_t bytes)->void* {
    void* p = ws + off;
    off += (bytes + 255) & ~(size_t)255;
    return p;
  };

  unsigned short* Wc   = (unsigned short*)alloc((size_t)3*1024*1024*2);
  unsigned short* W1T  = (unsigned short*)alloc((size_t)2*256*512*2);
  unsigned short* W2T  = (unsigned short*)alloc((size_t)2*256*256*2);
  unsigned short* xall = (unsigned short*)alloc((size_t)N_NODES*512*2);
  unsigned short* adjb = (unsigned short*)alloc((size_t)2*ADJSTR*2);
  unsigned short* xw1T = (unsigned short*)alloc((size_t)2*BTSTR*2);
  unsigned short* hbuf = (unsigned short*)alloc((size_t)2*NTOT*2);
  unsigned short* hw2T = (unsigned short*)alloc((size_t)2*BTSTR*2);
  float* parts = (float*)alloc((size_t)2*PSTR*4);      // aliased as C1 (64 MB)
  float* Zf    = (float*)alloc((size_t)2*NTOT*4);
  float* spart = (float*)alloc((size_t)2*N_NODES*2*4);
  float* stats = (float*)alloc((size_t)32*4);
  float* C1    = parts;
  float* outp  = (float*)d_out;

  // weight casts
  cast_wc<<<3072, 256, 0, stream>>>(dA_W, dA_Wr, tA_W, tA_Wr, sA_W, sA_Wr, Wc);
  transpose_cast<<<512, 256, 0, stream>>>(dG_W1, W1T,            512, 256);
  transpose_cast<<<512, 256, 0, stream>>>(tG_W1, W1T + 256*512,  512, 256);
  transpose_cast<<<256, 256, 0, stream>>>(dG_W2, W2T,            256, 256);
  transpose_cast<<<256, 256, 0, stream>>>(tG_W2, W2T + 256*256,  256, 256);

  // adapters (one grouped dispatch) then fuse
  adapt_gemm<<<496, 512, 0, stream>>>(drug_feats, target_feats, disease_feats, Wc, C1);
  adapter_fuse<<<N_NODES, 256, 0, stream>>>(C1,
      dA_b, dA_g, dA_be, dA_br,
      tA_b, tA_g, tA_be, tA_br,
      sA_b, sA_g, sA_be, sA_br, xall);

  // xw1T[b][n][node] = (x_all @ W1_b)^T, bf16, zero-filled nodes 7823..8191
  gemmS<<<2*128, 512, 0, stream>>>(
      xall, 0, 512, W1T, 256*512, 512,
      N_NODES, 128, 8, xw1T, BTSTR, KPAD);

  // mean+cast both adjs (real cols only; pads never contribute)
  mean_cast_row<<<dim3(N_NODES, 2), 256, 0, stream>>>(drug_adjs, target_adjs, adjb);

  // spmm1: parts[b][ks] = adjb[b] @ xw1[b]
  spmmK<<<496, 512, 0, stream>>>(adjb, xw1T, parts);

  reduce_prelu2<<<dim3(N_NODES,2), 256, 0, stream>>>(parts, dG_a, tG_a, hbuf);

  // hw2T[b][n][node] = (h_b @ W2_b)^T
  gemmS<<<2*128, 512, 0, stream>>>(
      hbuf, (long long)NTOT, 256, W2T, 256*256, 256,
      N_NODES, 128, 4, hw2T, BTSTR, KPAD);

  // spmm2: parts[b][ks] = adjb[b] @ hw2[b]
  spmmK<<<496, 512, 0, stream>>>(adjb, hw2T, parts);

  reduce_stats2<<<dim3(N_NODES,2), 256, 0, stream>>>(parts, Zf, spart);
  stats_final2<<<2, 256, 0, stream>>>(spart, stats);

  finalize<<<N_DRUG, 256, 0, stream>>>(Zf, stats, outp, 0, 0LL);
  finalize<<<N_TGT, 256, 0, stream>>>(Zf + NTOT, stats + 16, outp, N_DRUG, (long long)N_DRUG*256);
}

// Round 15
// 830.911 us; speedup vs baseline: 1.4765x; 1.0141x over previous
//
#include <hip/hip_runtime.h>
#include <hip/hip_bf16.h>
#include <stdint.h>

typedef __attribute__((ext_vector_type(8))) short short8;
typedef __attribute__((ext_vector_type(4))) float f32x4;

#define N_DRUG 708
#define N_TGT  1512
#define N_NODES 7823
#define N_D_T  2220          // 708+1512
#define KPAD   8192          // 128 * 64
#define MROWP  7936          // 31 * 256 (adjb row pad)
#define NTOT   2002688       // 7823*256
#define NSPLIT 2
#define PLANE  61199329LL    // 7823*7823
#define ADJSTR ((long long)MROWP*KPAD)     // adjb batch stride (elems)
#define BTSTR  ((long long)256*KPAD)       // xw1T/hw2T batch stride
#define PSTR   ((long long)NSPLIT*NTOT)    // parts batch stride

__device__ __forceinline__ unsigned short f2bf(float f) {
  union { float f; unsigned int i; } v; v.f = f;
  unsigned int r = v.i + 0x7FFF + ((v.i >> 16) & 1);
  return (unsigned short)(r >> 16);
}

__device__ __forceinline__ int4 pack8(const float v[8]) {
  union { int4 i4; unsigned short u[8]; } r;
  #pragma unroll
  for (int j = 0; j < 8; j++) r.u[j] = f2bf(v[j]);
  return r.i4;
}

// ---------------------------------------------------------------- cast kernels

__global__ __launch_bounds__(256) void cast_wc(
    const float* __restrict__ w0, const float* __restrict__ wr0,
    const float* __restrict__ w1, const float* __restrict__ wr1,
    const float* __restrict__ w2, const float* __restrict__ wr2,
    unsigned short* __restrict__ Wc)
{
  long long i4 = ((long long)blockIdx.x*256 + threadIdx.x)*4;
  int g  = (int)(i4 >> 20);
  int rr = (int)((i4 >> 10) & 1023);
  int c  = (int)(i4 & 1023);
  const float* src = (g==0) ? (rr<512?w0:wr0) : (g==1) ? (rr<512?w1:wr1) : (rr<512?w2:wr2);
  float4 f = *(const float4*)(src + (long long)(rr & 511)*1024 + c);
  ushort4 v; v.x=f2bf(f.x); v.y=f2bf(f.y); v.z=f2bf(f.z); v.w=f2bf(f.w);
  *(ushort4*)&Wc[i4] = v;
}

__global__ __launch_bounds__(256) void transpose_cast(
    const float* __restrict__ src, unsigned short* __restrict__ dst, int R, int C)
{
  int i = blockIdx.x*256 + threadIdx.x;
  if (i >= R*C) return;
  int r = i / C, c = i - r*C;
  dst[c*R + r] = f2bf(src[i]);
}

// mean of two f32 planes -> bf16 [MROWP][KPAD]; one block per (row, batch).
__global__ __launch_bounds__(256) void mean_cast_row(
    const float* __restrict__ A0, const float* __restrict__ A1,
    unsigned short* __restrict__ D)
{
  int row = blockIdx.x;
  const float* p0 = (blockIdx.y ? A1 : A0) + (long long)row*N_NODES;
  const float* p1 = p0 + PLANE;
  unsigned short* d = D + (long long)blockIdx.y*ADJSTR + (long long)row*KPAD;

  for (int c = threadIdx.x*8; c < 7816; c += 2048) {
    float4 a0 = *(const float4*)(p0+c);
    float4 a1 = *(const float4*)(p0+c+4);
    float4 b0 = *(const float4*)(p1+c);
    float4 b1 = *(const float4*)(p1+c+4);
    float v[8] = {0.5f*(a0.x+b0.x), 0.5f*(a0.y+b0.y), 0.5f*(a0.z+b0.z), 0.5f*(a0.w+b0.w),
                  0.5f*(a1.x+b1.x), 0.5f*(a1.y+b1.y), 0.5f*(a1.z+b1.z), 0.5f*(a1.w+b1.w)};
    *(int4*)(d + c) = pack8(v);
  }
  int t = threadIdx.x;
  if (t < 7) {                      // cols 7816..7822
    int c = 7816 + t;
    d[c] = f2bf(0.5f*(p0[c] + p1[c]));
  }
}

// ---------------------------------------------------------------- spmm (counted-wait pipeline)
// parts[b][ks][m][n] = adjb[b][m][k] * BT[b][n][k] over k-chunk ks (4096 k).
// Block 256M x 128N, 8 waves (each 32M x 128N, acc[2][8]).
// A: direct global->reg, 4-kt-deep rolling prefetch (never drained: raw barriers).
// B: double-buffered LDS 2 x (128n x 256k = 64KB), XOR-swizzled; regs for sub+1
//    in flight across barriers; compiler inserts counted vmcnt before ds_write.
// Grid 248 = 4 (b,ks) groups x 62 = ONE block-round on 256 CUs; XCD swizzle
// (248 = 8 x 31) -> each (b,ks) group spans 2 XCDs (B slice 2MB, L2-resident).
__global__ __launch_bounds__(512, 2) void spmmK(
    const unsigned short* __restrict__ Abase,
    const unsigned short* __restrict__ Bbase,
    float* __restrict__ parts)
{
  __shared__ __align__(16) unsigned short Bs[2][128*256];  // 2 x 64 KB

  int bid = (blockIdx.x & 7)*31 + (blockIdx.x >> 3);
  int grp = bid / 62;              // 0..3 -> (b, ks)
  int q   = bid % 62;
  int b  = grp >> 1;
  int ks = grp & 1;
  int mt = q >> 1, nt = q & 1;

  const unsigned short* A  = Abase + b*ADJSTR;
  const unsigned short* BT = Bbase + b*BTSTR;
  int m0 = mt*256, n0 = nt*128;
  int kt0 = ks*64;                 // 64 kt of 64 k; 16 subs of 4 kt

  int tid = threadIdx.x, lane = tid & 63, w = tid >> 6;
  int grow = m0 + w*32 + (lane&15);
  long long rA0 = (long long)grow*KPAD + (lane>>4)*8;

  f32x4 acc[2][8] = {};

  int srow[8], sslot[8];
  #pragma unroll
  for (int i=0;i<8;i++){ int c = i*512 + tid; srow[i] = c>>5; sslot[i] = c&31; }

  int4 breg[8];
  auto loadB = [&](int sub){
    long long kb = (long long)kt0*64 + sub*256;
    #pragma unroll
    for (int i=0;i<8;i++)
      breg[i] = *(const int4*)(BT + (long long)(n0+srow[i])*KPAD + kb + sslot[i]*8);
  };
  auto storeB = [&](unsigned short* buf){
    #pragma unroll
    for (int i=0;i<8;i++)
      *(int4*)(buf + srow[i]*256 + (sslot[i]^(srow[i]&7))*8) = breg[i];
  };
  auto loadA = [&](int g, int4* a){
    const unsigned short* p = A + rA0 + (long long)g*64;
    a[0] = *(const int4*)(p);
    a[1] = *(const int4*)(p + 16*KPAD);
    a[2] = *(const int4*)(p + 32);
    a[3] = *(const int4*)(p + 16*KPAD + 32);
  };
  auto compute = [&](int lt, const int4* a, const unsigned short* buf){
    #pragma unroll
    for (int kk=0; kk<2; ++kk) {
      short8 bv[8];
      #pragma unroll
      for (int nf=0; nf<8; ++nf) {
        int row = nf*16 + (lane&15);
        int sl  = (lt*8 + kk*4 + (lane>>4)) ^ (lane&7);
        bv[nf] = *(const short8*)&buf[row*256 + sl*8];
      }
      #pragma unroll
      for (int mf=0; mf<2; ++mf) {
        short8 av = *(const short8*)&a[kk*2+mf];
        #pragma unroll
        for (int nf=0; nf<8; ++nf)
          acc[mf][nf] = __builtin_amdgcn_mfma_f32_16x16x32_bf16(av, bv[nf], acc[mf][nf], 0, 0, 0);
      }
    }
  };

  int gmax = kt0 + 63;
  int4 a0[4], a1[4], a2[4], a3[4];

  // prologue: stage sub 0, issue B[1] and A[kt0..kt0+3]
  loadB(0);
  loadA(kt0+0, a0);
  loadA(kt0+1, a1);
  loadA(kt0+2, a2);
  loadA(kt0+3, a3);
  storeB(&Bs[0][0]);               // compiler waits (counted) for breg only
  loadB(1);
  asm volatile("s_waitcnt lgkmcnt(0)" ::: "memory");
  __builtin_amdgcn_s_barrier();
  __builtin_amdgcn_sched_barrier(0);

  int cur = 0;
  #pragma unroll 1
  for (int sub = 0; sub < 16; ++sub) {
    const unsigned short* Bc = &Bs[cur][0];
    int g = kt0 + sub*4;
    compute(0, a0, Bc); loadA(min(g+4, gmax), a0);
    compute(1, a1, Bc); loadA(min(g+5, gmax), a1);
    compute(2, a2, Bc); loadA(min(g+6, gmax), a2);
    compute(3, a3, Bc); loadA(min(g+7, gmax), a3);
    if (sub < 15) {
      __builtin_amdgcn_s_barrier();          // all waves done reading Bs[cur^1]
      __builtin_amdgcn_sched_barrier(0);
      storeB(&Bs[cur^1][0]);                 // counted vmcnt for breg
      loadB(min(sub+2, 15));
      asm volatile("s_waitcnt lgkmcnt(0)" ::: "memory");
      __builtin_amdgcn_s_barrier();          // Bs[cur^1] visible to all
      __builtin_amdgcn_sched_barrier(0);
      cur ^= 1;
    }
  }

  float* P = parts + b*PSTR + (long long)ks*NTOT;
  #pragma unroll
  for (int mf=0; mf<2; ++mf) {
    int mb = m0 + w*32 + mf*16 + ((lane>>4)<<2);
    #pragma unroll
    for (int i=0;i<4;i++){
      int m = mb + i;
      if (m < N_NODES) {
        #pragma unroll
        for (int nf=0; nf<8; ++nf) {
          int n = n0 + nf*16 + (lane&15);
          P[(long long)m*256 + n] = acc[mf][nf][i];
        }
      }
    }
  }
}

// ---------------------------------------------------------------- batched small GEMM (bf16 A, transposed bf16 store)
#define BN 256
#define BK 64

__global__ __launch_bounds__(512, 4) void gemmS(
    const unsigned short* __restrict__ Abase, long long a_bstr, int lda,
    const unsigned short* __restrict__ Bbase, long long b_bstr, int ldb,
    int m_cnt, int tiles_m, int ktiles,
    unsigned short* __restrict__ CTb, long long ct_bstr, int ldct)
{
  __shared__ __align__(16) unsigned short As[64*BK];
  __shared__ __align__(16) unsigned short Bs[BN*BK];

  int bid = blockIdx.x;
  int b   = bid / tiles_m;
  int tm  = bid % tiles_m;

  const unsigned short* A  = Abase + b*a_bstr;
  const unsigned short* BT = Bbase + b*b_bstr;

  int m0 = tm*64;
  int tid = threadIdx.x;
  int lane = tid & 63, w = tid >> 6;
  int wm = (w >> 2)*32, wn = (w & 3)*64;

  f32x4 acc[2][4] = {};

  int arow, aslot, brow[4], bslot[4];
  { int c = tid; arow = c>>3; aslot = c&7; }
  #pragma unroll
  for (int i=0;i<4;i++){ int c = i*512 + tid; brow[i] = c>>3; bslot[i] = c&7; }

  int4 ra, rb[4];
  auto loadAB = [&](int kt){
    int gr = m0 + arow; if (gr > m_cnt-1) gr = m_cnt-1;
    ra = *(const int4*)(A + (long long)gr*lda + kt*BK + aslot*8);
    #pragma unroll
    for (int i=0;i<4;i++)
      rb[i] = *(const int4*)(BT + (long long)brow[i]*ldb + kt*BK + bslot[i]*8);
  };
  auto storeAB = [&](){
    *(int4*)(As + arow*BK + (aslot^(arow&7))*8) = ra;
    #pragma unroll
    for (int i=0;i<4;i++)
      *(int4*)(Bs + brow[i]*BK + (bslot[i]^(brow[i]&7))*8) = rb[i];
  };

  loadAB(0);
  for (int kt = 0; kt < ktiles; ++kt) {
    __syncthreads();
    storeAB();
    __syncthreads();
    if (kt+1 < ktiles) loadAB(kt+1);
    #pragma unroll
    for (int kk=0; kk<2; ++kk) {
      short8 av[2], bv[4];
      #pragma unroll
      for (int x=0;x<2;x++){
        int row = wm + x*16 + (lane&15);
        int slot = kk*4 + (lane>>4);
        av[x] = *(const short8*)&As[row*BK + (slot^(row&7))*8];
      }
      #pragma unroll
      for (int x=0;x<4;x++){
        int row = wn + x*16 + (lane&15);
        int slot = kk*4 + (lane>>4);
        bv[x] = *(const short8*)&Bs[row*BK + (slot^(row&7))*8];
      }
      #pragma unroll
      for (int mf=0; mf<2; ++mf)
        #pragma unroll
        for (int nf=0; nf<4; ++nf)
          acc[mf][nf] = __builtin_amdgcn_mfma_f32_16x16x32_bf16(av[mf], bv[nf], acc[mf][nf], 0, 0, 0);
    }
  }

  unsigned short* CT = CTb + b*ct_bstr;
  #pragma unroll
  for (int nf=0; nf<4; ++nf) {
    int n = wn + nf*16 + (lane&15);
    #pragma unroll
    for (int mf=0; mf<2; ++mf) {
      int mb = m0 + wm + mf*16 + ((lane>>4)<<2);
      ushort4 v;
      v.x = (mb+0 < m_cnt) ? f2bf(acc[mf][nf][0]) : (unsigned short)0;
      v.y = (mb+1 < m_cnt) ? f2bf(acc[mf][nf][1]) : (unsigned short)0;
      v.z = (mb+2 < m_cnt) ? f2bf(acc[mf][nf][2]) : (unsigned short)0;
      v.w = (mb+3 < m_cnt) ? f2bf(acc[mf][nf][3]) : (unsigned short)0;
      *(ushort4*)&CT[(long long)n*ldct + mb] = v;
    }
  }
}

// ---------------------------------------------------------------- adapter GEMM (grouped, f32 A)
__global__ __launch_bounds__(512, 4) void adapt_gemm(
    const float* __restrict__ f0, const float* __restrict__ f1, const float* __restrict__ f2,
    const unsigned short* __restrict__ Wc, float* __restrict__ C1)
{
  __shared__ __align__(16) unsigned short As[64*BK];
  __shared__ __align__(16) unsigned short Bs[BN*BK];

  int bid = blockIdx.x;
  int tn = bid & 3, tq = bid >> 2;
  int g, lt, m_cnt, gstart;
  if (tq < 12)      { g=0; lt=tq;    m_cnt=N_DRUG;           gstart=0; }
  else if (tq < 36) { g=1; lt=tq-12; m_cnt=N_TGT;            gstart=N_DRUG; }
  else              { g=2; lt=tq-36; m_cnt=N_NODES-N_D_T;    gstart=N_D_T; }
  const float* A = (g==0) ? f0 : (g==1) ? f1 : f2;
  const unsigned short* BT = Wc + (long long)g*1024*1024;

  int m0 = lt*64, n0 = tn*BN;
  int tid = threadIdx.x;
  int lane = tid & 63, w = tid >> 6;
  int wm = (w >> 2)*32, wn = (w & 3)*64;

  f32x4 acc[2][4] = {};

  int arow, aslot, brow[4], bslot[4];
  { int c = tid; arow = c>>3; aslot = c&7; }
  #pragma unroll
  for (int i=0;i<4;i++){ int c = i*512 + tid; brow[i] = c>>3; bslot[i] = c&7; }

  int4 ra, rb[4];
  auto loadAB = [&](int kt){
    int gr = m0 + arow; if (gr > m_cnt-1) gr = m_cnt-1;
    const float* p = A + (long long)gr*1024 + kt*BK + aslot*8;
    float4 q0 = *(const float4*)p;
    float4 q1 = *(const float4*)(p+4);
    float v[8] = {q0.x,q0.y,q0.z,q0.w,q1.x,q1.y,q1.z,q1.w};
    ra = pack8(v);
    #pragma unroll
    for (int i=0;i<4;i++)
      rb[i] = *(const int4*)(BT + (long long)(n0 + brow[i])*1024 + kt*BK + bslot[i]*8);
  };
  auto storeAB = [&](){
    *(int4*)(As + arow*BK + (aslot^(arow&7))*8) = ra;
    #pragma unroll
    for (int i=0;i<4;i++)
      *(int4*)(Bs + brow[i]*BK + (bslot[i]^(brow[i]&7))*8) = rb[i];
  };

  loadAB(0);
  for (int kt = 0; kt < 16; ++kt) {
    __syncthreads();
    storeAB();
    __syncthreads();
    if (kt+1 < 16) loadAB(kt+1);
    #pragma unroll
    for (int kk=0; kk<2; ++kk) {
      short8 av[2], bv[4];
      #pragma unroll
      for (int x=0;x<2;x++){
        int row = wm + x*16 + (lane&15);
        int slot = kk*4 + (lane>>4);
        av[x] = *(const short8*)&As[row*BK + (slot^(row&7))*8];
      }
      #pragma unroll
      for (int x=0;x<4;x++){
        int row = wn + x*16 + (lane&15);
        int slot = kk*4 + (lane>>4);
        bv[x] = *(const short8*)&Bs[row*BK + (slot^(row&7))*8];
      }
      #pragma unroll
      for (int mf=0; mf<2; ++mf)
        #pragma unroll
        for (int nf=0; nf<4; ++nf)
          acc[mf][nf] = __builtin_amdgcn_mfma_f32_16x16x32_bf16(av[mf], bv[nf], acc[mf][nf], 0, 0, 0);
    }
  }

  #pragma unroll
  for (int mf=0; mf<2; ++mf) {
    int mb = m0 + wm + mf*16 + ((lane>>4)<<2);
    #pragma unroll
    for (int i=0;i<4;i++){
      int m = mb + i;
      if (m < m_cnt) {
        #pragma unroll
        for (int nf=0; nf<4; ++nf) {
          int n = n0 + wn + nf*16 + (lane&15);
          C1[(long long)(gstart+m)*1024 + n] = acc[mf][nf][i];
        }
      }
    }
  }
}

// ---------------------------------------------------------------- fused epilogues

__global__ __launch_bounds__(256) void adapter_fuse(
    const float* __restrict__ C1,
    const float* __restrict__ b0, const float* __restrict__ g0, const float* __restrict__ be0, const float* __restrict__ br0,
    const float* __restrict__ b1, const float* __restrict__ g1, const float* __restrict__ be1, const float* __restrict__ br1,
    const float* __restrict__ b2, const float* __restrict__ g2, const float* __restrict__ be2, const float* __restrict__ br2,
    unsigned short* __restrict__ xall)
{
  int r = blockIdx.x;
  const float *b, *g, *be, *br;
  if (r < N_DRUG)     { b=b0; g=g0; be=be0; br=br0; }
  else if (r < N_D_T) { b=b1; g=g1; be=be1; br=br1; }
  else                { b=b2; g=g2; be=be2; br=br2; }
  int t = threadIdx.x;
  const float* row = C1 + (long long)r*1024;
  float ya = row[t]       + b[t];
  float yb = row[t + 256] + b[t + 256];
  float s = ya + yb, q = ya*ya + yb*yb;
  #pragma unroll
  for (int o=32;o;o>>=1){ s += __shfl_down(s,o); q += __shfl_down(q,o); }
  __shared__ float ss[4], qq[4];
  if ((t & 63) == 0) { ss[t>>6]=s; qq[t>>6]=q; }
  __syncthreads();
  float S = ss[0]+ss[1]+ss[2]+ss[3];
  float Q = qq[0]+qq[1]+qq[2]+qq[3];
  float mean = S * (1.f/512.f);
  float var  = Q * (1.f/512.f) - mean*mean;
  float inv  = rsqrtf(var + 1e-5f);
  float za = fmaxf((ya-mean)*inv*g[t]     + be[t],     0.f);
  float zb = fmaxf((yb-mean)*inv*g[t+256] + be[t+256], 0.f);
  float ha = za + row[512 + t] + br[t];
  float hb = zb + row[768 + t] + br[t + 256];
  ha = (ha > 0.f) ? ha : (expf(ha) - 1.f);
  hb = (hb > 0.f) ? hb : (expf(hb) - 1.f);
  xall[(long long)r*512 + t]       = f2bf(ha);
  xall[(long long)r*512 + t + 256] = f2bf(hb);
}

__global__ __launch_bounds__(256) void reduce_prelu2(
    const float* __restrict__ parts, const float* __restrict__ a0, const float* __restrict__ a1,
    unsigned short* __restrict__ h)
{
  int b = blockIdx.y;
  long long i = (long long)blockIdx.x*256 + threadIdx.x;
  const float* P = parts + b*PSTR;
  float s = P[i] + P[NTOT + i];
  float a = (b ? a1 : a0)[0];
  h[b*(long long)NTOT + i] = f2bf(s >= 0.f ? s : a*s);
}

__global__ __launch_bounds__(256) void reduce_stats2(
    const float* __restrict__ parts, float* __restrict__ Z, float* __restrict__ sp)
{
  int b = blockIdx.y;
  long long i = (long long)blockIdx.x*256 + threadIdx.x;
  const float* P = parts + b*PSTR;
  float s = P[i] + P[NTOT + i];
  Z[b*(long long)NTOT + i] = s;
  float a = s, q = s*s;
  #pragma unroll
  for (int o=32;o;o>>=1){ a += __shfl_down(a,o); q += __shfl_down(q,o); }
  __shared__ float ss[4], qq[4];
  int t = threadIdx.x;
  if ((t&63)==0){ ss[t>>6]=a; qq[t>>6]=q; }
  __syncthreads();
  if (t==0) {
    sp[(long long)b*2*N_NODES + 2*blockIdx.x]   = ss[0]+ss[1]+ss[2]+ss[3];
    sp[(long long)b*2*N_NODES + 2*blockIdx.x+1] = qq[0]+qq[1]+qq[2]+qq[3];
  }
}

__global__ __launch_bounds__(256) void stats_final2(
    const float* __restrict__ sp, float* __restrict__ stats)
{
  int b = blockIdx.x;
  const float* S = sp + (long long)b*2*N_NODES;
  int t = threadIdx.x;
  float s = 0.f, q = 0.f;
  for (int i=t; i<N_NODES; i+=256){ s += S[2*i]; q += S[2*i+1]; }
  #pragma unroll
  for (int o=32;o;o>>=1){ s += __shfl_down(s,o); q += __shfl_down(q,o); }
  __shared__ float ss[4], qq[4];
  if ((t&63)==0){ ss[t>>6]=s; qq[t>>6]=q; }
  __syncthreads();
  if (t==0){ stats[b*16]=ss[0]+ss[1]+ss[2]+ss[3]; stats[b*16+1]=qq[0]+qq[1]+qq[2]+qq[3]; }
}

__global__ __launch_bounds__(256) void finalize(
    const float* __restrict__ Z, const float* __restrict__ stats,
    float* __restrict__ out, int row_lo, long long out_off)
{
  int r = row_lo + blockIdx.x;
  int t = threadIdx.x;
  float mean = stats[0] * (1.f/(float)NTOT);
  float var  = stats[1] * (1.f/(float)NTOT) - mean*mean;
  float inv  = rsqrtf(var + 1e-5f);
  float z = (Z[(long long)r*256 + t] - mean) * inv;
  float q = z*z;
  #pragma unroll
  for (int o=32;o;o>>=1) q += __shfl_down(q,o);
  __shared__ float qq[4];
  if ((t&63)==0) qq[t>>6]=q;
  __syncthreads();
  float norm = sqrtf(qq[0]+qq[1]+qq[2]+qq[3]);
  out[out_off + (long long)blockIdx.x*256 + t] = z / (norm + 1e-8f);
}

// ---------------------------------------------------------------- launcher

extern "C" void kernel_launch(void* const* d_in, const int* in_sizes, int n_in,
                              void* d_out, int out_size, void* d_ws, size_t ws_size,
                              hipStream_t stream)
{
  const float* drug_feats    = (const float*)d_in[0];
  const float* target_feats  = (const float*)d_in[1];
  const float* disease_feats = (const float*)d_in[2];
  const float* drug_adjs     = (const float*)d_in[3];
  const float* target_adjs   = (const float*)d_in[4];
  const float* dA_W  = (const float*)d_in[5];
  const float* dA_b  = (const float*)d_in[6];
  const float* dA_g  = (const float*)d_in[7];
  const float* dA_be = (const float*)d_in[8];
  const float* dA_Wr = (const float*)d_in[9];
  const float* dA_br = (const float*)d_in[10];
  const float* tA_W  = (const float*)d_in[11];
  const float* tA_b  = (const float*)d_in[12];
  const float* tA_g  = (const float*)d_in[13];
  const float* tA_be = (const float*)d_in[14];
  const float* tA_Wr = (const float*)d_in[15];
  const float* tA_br = (const float*)d_in[16];
  const float* sA_W  = (const float*)d_in[17];
  const float* sA_b  = (const float*)d_in[18];
  const float* sA_g  = (const float*)d_in[19];
  const float* sA_be = (const float*)d_in[20];
  const float* sA_Wr = (const float*)d_in[21];
  const float* sA_br = (const float*)d_in[22];
  const float* dG_W1 = (const float*)d_in[23];
  const float* dG_W2 = (const float*)d_in[24];
  const float* tG_W1 = (const float*)d_in[25];
  const float* tG_W2 = (const float*)d_in[26];
  const float* dG_a  = (const float*)d_in[27];
  const float* tG_a  = (const float*)d_in[28];

  char* ws = (char*)d_ws;
  size_t off = 0;
  auto alloc = [&](size_t bytes)->void* {
    void* p = ws + off;
    off += (bytes + 255) & ~(size_t)255;
    return p;
  };

  unsigned short* Wc   = (unsigned short*)alloc((size_t)3*1024*1024*2);
  unsigned short* W1T  = (unsigned short*)alloc((size_t)2*256*512*2);
  unsigned short* W2T  = (unsigned short*)alloc((size_t)2*256*256*2);
  unsigned short* xall = (unsigned short*)alloc((size_t)N_NODES*512*2);
  unsigned short* adjb = (unsigned short*)alloc((size_t)2*ADJSTR*2);
  unsigned short* xw1T = (unsigned short*)alloc((size_t)2*BTSTR*2);
  unsigned short* hbuf = (unsigned short*)alloc((size_t)2*NTOT*2);
  unsigned short* hw2T = (unsigned short*)alloc((size_t)2*BTSTR*2);
  float* parts = (float*)alloc((size_t)2*PSTR*4);      // aliased as C1 (32 MB)
  float* Zf    = (float*)alloc((size_t)2*NTOT*4);
  float* spart = (float*)alloc((size_t)2*N_NODES*2*4);
  float* stats = (float*)alloc((size_t)32*4);
  float* C1    = parts;
  float* outp  = (float*)d_out;

  // weight casts
  cast_wc<<<3072, 256, 0, stream>>>(dA_W, dA_Wr, tA_W, tA_Wr, sA_W, sA_Wr, Wc);
  transpose_cast<<<512, 256, 0, stream>>>(dG_W1, W1T,            512, 256);
  transpose_cast<<<512, 256, 0, stream>>>(tG_W1, W1T + 256*512,  512, 256);
  transpose_cast<<<256, 256, 0, stream>>>(dG_W2, W2T,            256, 256);
  transpose_cast<<<256, 256, 0, stream>>>(tG_W2, W2T + 256*256,  256, 256);

  // adapters (one grouped dispatch) then fuse
  adapt_gemm<<<496, 512, 0, stream>>>(drug_feats, target_feats, disease_feats, Wc, C1);
  adapter_fuse<<<N_NODES, 256, 0, stream>>>(C1,
      dA_b, dA_g, dA_be, dA_br,
      tA_b, tA_g, tA_be, tA_br,
      sA_b, sA_g, sA_be, sA_br, xall);

  // xw1T[b][n][node] = (x_all @ W1_b)^T, bf16, zero-filled nodes 7823..8191
  gemmS<<<2*128, 512, 0, stream>>>(
      xall, 0, 512, W1T, 256*512, 512,
      N_NODES, 128, 8, xw1T, BTSTR, KPAD);

  // mean+cast both adjs (real cols only; pads never contribute)
  mean_cast_row<<<dim3(N_NODES, 2), 256, 0, stream>>>(drug_adjs, target_adjs, adjb);

  // spmm1: parts[b][ks] = adjb[b] @ xw1[b]   (248 blocks = one round)
  spmmK<<<248, 512, 0, stream>>>(adjb, xw1T, parts);

  reduce_prelu2<<<dim3(N_NODES,2), 256, 0, stream>>>(parts, dG_a, tG_a, hbuf);

  // hw2T[b][n][node] = (h_b @ W2_b)^T
  gemmS<<<2*128, 512, 0, stream>>>(
      hbuf, (long long)NTOT, 256, W2T, 256*256, 256,
      N_NODES, 128, 4, hw2T, BTSTR, KPAD);

  // spmm2: parts[b][ks] = adjb[b] @ hw2[b]
  spmmK<<<248, 512, 0, stream>>>(adjb, hw2T, parts);

  reduce_stats2<<<dim3(N_NODES,2), 256, 0, stream>>>(parts, Zf, spart);
  stats_final2<<<2, 256, 0, stream>>>(spart, stats);

  finalize<<<N_DRUG, 256, 0, stream>>>(Zf, stats, outp, 0, 0LL);
  finalize<<<N_TGT, 256, 0, stream>>>(Zf + NTOT, stats + 16, outp, N_DRUG, (long long)N_DRUG*256);
}